// Round 2
// baseline (319.535 us; speedup 1.0000x reference)
//
#include <hip/hip_runtime.h>
#include <math.h>

// SPP: out = concat(x, mp5(x), mp9(x), mp13(x)) along channels.
// x: (32, 512, 32, 32) fp32 -> out: (32, 2048, 32, 32) fp32.
// Identities: mp9 = mp5(mp5(x)), mp13 = mp5(mp9(x)); mp5 separable.
//
// Structure: 1 wave owns 2 (n,c) planes resident in LDS. All LDS
// producer/consumer dependencies are intra-wave (DS ops retire in order
// per wave, and the writeback values are data-dependent on the reads)
// -> NO __syncthreads anywhere, no double buffering.
// Per stage: column pass reads 5 row-clamped rows via ds_read_b128
// (row-clamping == -inf padding for max), horizontal pass is pure
// registers, result written back in place, then read back coalesced for
// the global store.
// LDS row stride = 36 floats (144 B): 16B-aligned b128 everywhere, and
// bank-uniform (8 words/bank per 1KB instruction — the minimum) for both
// the coalesced staging pattern and the per-row column-pass pattern.

constexpr int STRF = 36;              // LDS row stride in floats (144 B)
constexpr int PLANE_LDS = 32 * STRF;  // 1152 floats per plane

__global__ __launch_bounds__(256, 4) void spp_kernel(
    const float* __restrict__ x, float* __restrict__ out) {
  // 4 waves * 2 planes * 4608 B = 36,864 B -> 4 blocks/CU (16 waves/CU)
  __shared__ __align__(16) float L[8 * PLANE_LDS];

  const int t = threadIdx.x;
  const int wv = t >> 6;                    // wave within block (0..3)
  const int l = t & 63;                     // lane
  const int pair = blockIdx.x * 4 + wv;     // this wave's plane pair
  const int plane0 = pair * 2;              // even plane index
  const int n = plane0 >> 9;                // batch
  const int c = plane0 & 511;               // channel (even)

  const int q = l >> 5;                     // which of the 2 planes
  const int r = l & 31;                     // row within plane

  // Global bases in float4 units. Planes (c, c+1) are contiguous in x and
  // in each 512-channel block of out (c even -> never crosses n).
  const float4* __restrict__ xin = (const float4*)x + (size_t)plane0 * 256;
  float4* __restrict__ oid = (float4*)out + ((size_t)n * 2048 + c) * 256;

  // LDS bases. Linear (row-padded) storage; global row g = k*8 + (l>>3)
  // spans both planes contiguously since PLANE_LDS = 32*STRF.
  float* const Lw = L + wv * 2 * PLANE_LDS;
  float* const stage_base = Lw + (l >> 3) * STRF + (l & 7) * 4;

  // ---- load (coalesced 1KB/instr), identity output, stage into LDS ----
  float4 v[8];
  #pragma unroll
  for (int k = 0; k < 8; ++k) v[k] = xin[k * 64 + l];
  #pragma unroll
  for (int k = 0; k < 8; ++k) oid[k * 64 + l] = v[k];
  #pragma unroll
  for (int k = 0; k < 8; ++k) *(float4*)(stage_base + k * 8 * STRF) = v[k];
  asm volatile("" ::: "memory");  // pin LDS op order vs compiler (free)

  // ---- per-lane row pointers (clamped neighbors; duplicates are
  //      harmless for max and exactly reproduce -inf padding) ----
  float* const rowp = Lw + q * PLANE_LDS + r * STRF;
  const int rm2 = (r >= 2) ? r - 2 : 0;
  const int rm1 = (r >= 1) ? r - 1 : 0;
  const int rp1 = (r <= 30) ? r + 1 : 31;
  const int rp2 = (r <= 29) ? r + 2 : 31;
  const float* const nbs[4] = {Lw + q * PLANE_LDS + rm2 * STRF,
                               Lw + q * PLANE_LDS + rm1 * STRF,
                               Lw + q * PLANE_LDS + rp1 * STRF,
                               Lw + q * PLANE_LDS + rp2 * STRF};

  #pragma unroll
  for (int p = 0; p < 3; ++p) {
    // ---- column pass: cm[c] = max over rows clamp(r-2..r+2) ----
    float cm[32];
    #pragma unroll
    for (int s = 0; s < 8; ++s) {
      const float4 u = *(const float4*)(rowp + s * 4);
      cm[s * 4 + 0] = u.x; cm[s * 4 + 1] = u.y;
      cm[s * 4 + 2] = u.z; cm[s * 4 + 3] = u.w;
    }
    #pragma unroll
    for (int j = 0; j < 4; ++j) {
      #pragma unroll
      for (int s = 0; s < 8; ++s) {
        const float4 u = *(const float4*)(nbs[j] + s * 4);
        cm[s * 4 + 0] = fmaxf(cm[s * 4 + 0], u.x);
        cm[s * 4 + 1] = fmaxf(cm[s * 4 + 1], u.y);
        cm[s * 4 + 2] = fmaxf(cm[s * 4 + 2], u.z);
        cm[s * 4 + 3] = fmaxf(cm[s * 4 + 3], u.w);
      }
    }

    // ---- row pass: pure registers, clamped window (static indices) ----
    float m[32];
    #pragma unroll
    for (int cc = 0; cc < 32; ++cc) {
      const int im2 = cc < 2 ? 0 : cc - 2;
      const int im1 = cc < 1 ? 0 : cc - 1;
      const int ip1 = cc > 30 ? 31 : cc + 1;
      const int ip2 = cc > 29 ? 31 : cc + 2;
      m[cc] = fmaxf(fmaxf(fmaxf(cm[im2], cm[im1]), fmaxf(cm[ip1], cm[ip2])),
                    cm[cc]);
    }

    // ---- write back in place: this is the next stage's input.
    // Safe without barrier: the written values are data-dependent on the
    // column-pass reads (lgkmcnt waits enforced by the compiler), and all
    // hazards are intra-wave.
    asm volatile("" ::: "memory");
    #pragma unroll
    for (int s = 0; s < 8; ++s) {
      *(float4*)(rowp + s * 4) =
          make_float4(m[s * 4 + 0], m[s * 4 + 1], m[s * 4 + 2], m[s * 4 + 3]);
    }
    asm volatile("" ::: "memory");

    // ---- coalesced read-back + store of this pyramid level ----
    float4* __restrict__ olev = oid + (size_t)(p + 1) * 131072;  // +512 ch
    #pragma unroll
    for (int k = 0; k < 8; ++k) {
      olev[k * 64 + l] = *(const float4*)(stage_base + k * 8 * STRF);
    }
    asm volatile("" ::: "memory");
  }
}

extern "C" void kernel_launch(void* const* d_in, const int* in_sizes, int n_in,
                              void* d_out, int out_size, void* d_ws,
                              size_t ws_size, hipStream_t stream) {
  const float* x = (const float*)d_in[0];
  float* out = (float*)d_out;
  // 16384 planes / (4 waves * 2 planes per wave) = 2048 blocks
  spp_kernel<<<2048, 256, 0, stream>>>(x, out);
}

// Round 3
// 317.491 us; speedup vs baseline: 1.0064x; 1.0064x over previous
//
#include <hip/hip_runtime.h>
#include <math.h>

// SPP: out = concat(x, mp5(x), mp9(x), mp13(x)) along channels.
// x: (32, 512, 32, 32) fp32 -> out: (32, 2048, 32, 32) fp32.
// Identities: mp9 = mp5(mp5(x)), mp13 = mp5(mp9(x)); mp5 separable.
//
// Round-2 structure: ONE plane per wave, HALF-ROW per lane.
//   lane l -> row r = l&31, half h = l>>5 (cols [16h, 16h+16)).
// All LDS hazards are intra-wave (single instruction stream, in-order DS
// pipe) -> zero __syncthreads. Per stage:
//   col pass : 5 row-clamped ds_read_b128 groups -> cm[16] in registers
//   boundary : 4 __shfl_xor(...,32) to fetch 2 edge columns from partner
//   row pass : pure-register max5 with static clamped indices
//   writeback: 4 ds_write_b128 in place; readback coalesced for store.
// Row clamping == -inf padding for max (duplicates are harmless).
//
// Occupancy: LDS 4*4608 = 18,432 B/block -> 8 blocks/CU = 32 waves/CU
// (full), and __launch_bounds__(256,8) targets the <=64-VGPR tier
// (~40 live by construction). This is the fix for round-1's regression
// (16 waves/CU + 128-VGPR pressure -> latency-bound at 2.2 TB/s).
//
// LDS row stride 36 floats (144 B): 16B-aligned b128 everywhere and
// bank-uniform (8 words/bank per wave instruction, the minimum) for the
// staging pattern, the 5-row column pattern, and the readback pattern.

constexpr int STRF = 36;              // LDS row stride in floats (144 B)
constexpr int PLANE_LDS = 32 * STRF;  // 1152 floats = 4608 B per plane

__device__ __forceinline__ float max5(float a, float b, float c, float d,
                                      float e) {
  return fmaxf(fmaxf(fmaxf(a, b), fmaxf(c, d)), e);
}

__global__ __launch_bounds__(256, 8) void spp_kernel(
    const float* __restrict__ x, float* __restrict__ out) {
  __shared__ __align__(16) float L[4 * PLANE_LDS];  // 18,432 B

  const int t = threadIdx.x;
  const int wv = t >> 6;                  // wave in block (0..3)
  const int l = t & 63;                   // lane
  const int plane = blockIdx.x * 4 + wv;  // this wave's (n,c) plane
  const int n = plane >> 9;
  const int c = plane & 511;
  const int r = l & 31;                   // row
  const int h = l >> 5;                   // column half

  const float4* __restrict__ xin = (const float4*)x + (size_t)plane * 256;
  float4* __restrict__ oid = (float4*)out + ((size_t)n * 2048 + c) * 256;

  float* const Lw = L + wv * PLANE_LDS;
  float* const stage_base = Lw + (l >> 3) * STRF + (l & 7) * 4;

  // ---- prologue: load (coalesced), identity store, stage to LDS ----
  float4 v0 = xin[l];
  float4 v1 = xin[64 + l];
  float4 v2 = xin[128 + l];
  float4 v3 = xin[192 + l];
  oid[l] = v0;
  oid[64 + l] = v1;
  oid[128 + l] = v2;
  oid[192 + l] = v3;
  *(float4*)(stage_base + 0 * 8 * STRF) = v0;
  *(float4*)(stage_base + 1 * 8 * STRF) = v1;
  *(float4*)(stage_base + 2 * 8 * STRF) = v2;
  *(float4*)(stage_base + 3 * 8 * STRF) = v3;
  asm volatile("" ::: "memory");

  // ---- per-lane row pointers (clamped; duplicates == -inf padding) ----
  float* const rp = Lw + r * STRF + h * 16;
  const int rm2 = (r >= 2) ? r - 2 : 0;
  const int rm1 = (r >= 1) ? r - 1 : 0;
  const int rq1 = (r <= 30) ? r + 1 : 31;
  const int rq2 = (r <= 29) ? r + 2 : 31;
  const float* const nb0 = Lw + rm2 * STRF + h * 16;
  const float* const nb1 = Lw + rm1 * STRF + h * 16;
  const float* const nb2 = Lw + rq1 * STRF + h * 16;
  const float* const nb3 = Lw + rq2 * STRF + h * 16;

  #pragma unroll
  for (int p = 0; p < 3; ++p) {
    // ---- column pass: cm[j] = max over rows clamp(r-2..r+2), col 16h+j
    float cm[16];
    #pragma unroll
    for (int s = 0; s < 4; ++s) {
      const float4 u = *(const float4*)(rp + s * 4);
      cm[s * 4 + 0] = u.x; cm[s * 4 + 1] = u.y;
      cm[s * 4 + 2] = u.z; cm[s * 4 + 3] = u.w;
    }
    #pragma unroll
    for (int s = 0; s < 4; ++s) {
      const float4 a = *(const float4*)(nb0 + s * 4);
      const float4 b = *(const float4*)(nb1 + s * 4);
      const float4 d = *(const float4*)(nb2 + s * 4);
      const float4 e = *(const float4*)(nb3 + s * 4);
      cm[s * 4 + 0] = max5(cm[s * 4 + 0], a.x, b.x, d.x, e.x);
      cm[s * 4 + 1] = max5(cm[s * 4 + 1], a.y, b.y, d.y, e.y);
      cm[s * 4 + 2] = max5(cm[s * 4 + 2], a.z, b.z, d.z, e.z);
      cm[s * 4 + 3] = max5(cm[s * 4 + 3], a.w, b.w, d.w, e.w);
    }

    // ---- cross-half boundary columns via shuffle (partner = l^32) ----
    const float s0 = __shfl_xor(cm[0], 32);    // partner col 16h'+0
    const float s1 = __shfl_xor(cm[1], 32);    // partner col 16h'+1
    const float s14 = __shfl_xor(cm[14], 32);  // partner col 16h'+14
    const float s15 = __shfl_xor(cm[15], 32);  // partner col 16h'+15

    // Extended window ext[i] = column-max at global col 16h + i - 2.
    float ext[20];
    ext[0] = h ? s14 : cm[0];    // h=0: clamp dup; h=1: col 14
    ext[1] = h ? s15 : cm[0];    // h=0: clamp dup; h=1: col 15
    #pragma unroll
    for (int i = 0; i < 16; ++i) ext[2 + i] = cm[i];
    ext[18] = h ? cm[15] : s0;   // h=0: col 16; h=1: clamp dup
    ext[19] = h ? cm[15] : s1;   // h=0: col 17; h=1: clamp dup

    // ---- row pass (registers) + in-place writeback, 4 cols at a time
    #pragma unroll
    for (int g = 0; g < 4; ++g) {
      float4 mw;
      mw.x = max5(ext[4 * g + 0], ext[4 * g + 1], ext[4 * g + 2],
                  ext[4 * g + 3], ext[4 * g + 4]);
      mw.y = max5(ext[4 * g + 1], ext[4 * g + 2], ext[4 * g + 3],
                  ext[4 * g + 4], ext[4 * g + 5]);
      mw.z = max5(ext[4 * g + 2], ext[4 * g + 3], ext[4 * g + 4],
                  ext[4 * g + 5], ext[4 * g + 6]);
      mw.w = max5(ext[4 * g + 3], ext[4 * g + 4], ext[4 * g + 5],
                  ext[4 * g + 6], ext[4 * g + 7]);
      *(float4*)(rp + g * 4) = mw;  // in-place: next stage's input
    }
    asm volatile("" ::: "memory");

    // ---- coalesced readback + store of this pyramid level ----
    float4* __restrict__ olev = oid + (size_t)(p + 1) * 131072;  // +512 ch
    olev[l]       = *(const float4*)(stage_base + 0 * 8 * STRF);
    olev[64 + l]  = *(const float4*)(stage_base + 1 * 8 * STRF);
    olev[128 + l] = *(const float4*)(stage_base + 2 * 8 * STRF);
    olev[192 + l] = *(const float4*)(stage_base + 3 * 8 * STRF);
    asm volatile("" ::: "memory");
  }
}

extern "C" void kernel_launch(void* const* d_in, const int* in_sizes, int n_in,
                              void* d_out, int out_size, void* d_ws,
                              size_t ws_size, hipStream_t stream) {
  const float* x = (const float*)d_in[0];
  float* out = (float*)d_out;
  // 16384 planes / (4 waves * 1 plane per wave) = 4096 blocks
  spp_kernel<<<4096, 256, 0, stream>>>(x, out);
}

// Round 4
// 302.393 us; speedup vs baseline: 1.0567x; 1.0499x over previous
//
#include <hip/hip_runtime.h>
#include <math.h>

// SPP: out = concat(x, mp5(x), mp9(x), mp13(x)) along channels.
// x: (32, 512, 32, 32) fp32 -> out: (32, 2048, 32, 32) fp32.
// Identities: mp9 = mp5(mp5(x)), mp13 = mp5(mp9(x)); mp5 separable.
//
// Round-3 structure = round-0 mapping (1 block per plane, 4 waves
// cooperate: thread t -> row r = t>>3, cols [(t&7)*4, +4)) with the
// round-2 algorithm:
//   - column pass FIRST: 5 row-clamped ds_read_b128 -> 4 col-maxes in reg
//     (row clamping == -inf padding for max; duplicate reads broadcast)
//   - row pass in REGISTERS: neighbor columns via 4 __shfl (lane +/-1
//     holds the adjacent 4 columns of the same row), edges get -inf
//   - level output stored STRAIGHT from registers (thread's 4 cols at
//     e0 = 4t is exactly the coalesced float4 store pattern)
//   - ping-pong LDS planes, ONE barrier per stage transition: stage p
//     reads cur / writes nxt; the barrier separates all cross-wave
//     (reads of cur | writes of nxt) from stage p+1's writes to cur.
// => per stage: 5 ds_read_b128 + 1 ds_write_b128 + 4 shfl, 3 barriers
// total (round 0: 8 ds_read_b32 + 7 b128 + 3 barriers per stage).
//
// Occupancy: LDS 9216 B/block -> 8 blocks/CU = 32 waves/CU (full);
// ~48 live VGPRs -> fits the 64-VGPR tier of __launch_bounds__(256,8)
// without spills (round 2 failed this: whole plane per wave).
//
// LDS row stride 36 floats: 16B-aligned b128 and bank-uniform
// (8 words/bank per wave instruction, the minimum) for the staging,
// 5-row column-pass, and writeback patterns.

constexpr int STRF = 36;             // LDS row stride in floats (144 B)
constexpr int PLANE = 32 * STRF;     // 1152 floats = 4608 B per plane

__device__ __forceinline__ float max5(float a, float b, float c, float d,
                                      float e) {
  return fmaxf(fmaxf(fmaxf(a, b), fmaxf(c, d)), e);
}

__global__ __launch_bounds__(256, 8) void spp_kernel(
    const float* __restrict__ x, float* __restrict__ out) {
  __shared__ __align__(16) float A[PLANE];
  __shared__ __align__(16) float B[PLANE];

  const int t = threadIdx.x;
  const int plane = blockIdx.x;        // n*512 + c
  const int n = plane >> 9;
  const int c = plane & 511;
  const int r = t >> 3;                // row 0..31
  const int c0 = (t & 7) * 4;          // col base 0..28

  const float4* __restrict__ xin = (const float4*)x + (size_t)plane * 256;
  float4* __restrict__ oid = (float4*)out + ((size_t)n * 2048 + c) * 256;

  // ---- prologue: coalesced load, identity store, stage to LDS ----
  float4 v = xin[t];
  oid[t] = v;
  *(float4*)(&A[r * STRF + c0]) = v;

  // Clamped row indices (duplicates == -inf padding for max).
  const int rm2 = (r < 2) ? 0 : r - 2;
  const int rm1 = (r < 1) ? 0 : r - 1;
  const int rp1 = (r > 30) ? 31 : r + 1;
  const int rp2 = (r > 29) ? 31 : r + 2;

  __syncthreads();

  float* cur = A;
  float* nxt = B;
  #pragma unroll
  for (int p = 0; p < 3; ++p) {
    // ---- column pass: 5 row-clamped b128 reads, 4 col-maxes ----
    const float4 u0 = *(const float4*)(cur + rm2 * STRF + c0);
    const float4 u1 = *(const float4*)(cur + rm1 * STRF + c0);
    const float4 u2 = *(const float4*)(cur + r   * STRF + c0);
    const float4 u3 = *(const float4*)(cur + rp1 * STRF + c0);
    const float4 u4 = *(const float4*)(cur + rp2 * STRF + c0);
    const float cm0 = max5(u0.x, u1.x, u2.x, u3.x, u4.x);  // col c0
    const float cm1 = max5(u0.y, u1.y, u2.y, u3.y, u4.y);  // col c0+1
    const float cm2 = max5(u0.z, u1.z, u2.z, u3.z, u4.z);  // col c0+2
    const float cm3 = max5(u0.w, u1.w, u2.w, u3.w, u4.w);  // col c0+3

    // ---- neighbor columns via shuffle (lane +/-1 == cols +/-4) ----
    const float sl2 = __shfl_up(cm2, 1);    // col c0-2 (from lane l-1)
    const float sl3 = __shfl_up(cm3, 1);    // col c0-1
    const float sr0 = __shfl_down(cm0, 1);  // col c0+4 (from lane l+1)
    const float sr1 = __shfl_down(cm1, 1);  // col c0+5
    const bool le = (c0 == 0);
    const bool re = (c0 == 28);
    const float e0 = le ? -INFINITY : sl2;
    const float e1 = le ? -INFINITY : sl3;
    const float e6 = re ? -INFINITY : sr0;
    const float e7 = re ? -INFINITY : sr1;

    // ---- row pass: window (col-2 .. col+2) per output col ----
    float4 m;
    m.x = max5(e0, e1, cm0, cm1, cm2);
    m.y = max5(e1, cm0, cm1, cm2, cm3);
    m.z = max5(cm0, cm1, cm2, cm3, e6);
    m.w = max5(cm1, cm2, cm3, e6, e7);

    // ---- level store straight from registers (coalesced) ----
    oid[(size_t)(p + 1) * 131072 + t] = m;  // +512 channels per level

    if (p < 2) {
      // Feed next stage: write the OTHER plane (races nothing), then one
      // barrier makes it visible and licenses stage p+1 to reuse cur.
      *(float4*)(&nxt[r * STRF + c0]) = m;
      __syncthreads();
      float* tmp = cur; cur = nxt; nxt = tmp;   // static after unroll
    }
  }
}

extern "C" void kernel_launch(void* const* d_in, const int* in_sizes, int n_in,
                              void* d_out, int out_size, void* d_ws,
                              size_t ws_size, hipStream_t stream) {
  const float* x = (const float*)d_in[0];
  float* out = (float*)d_out;
  spp_kernel<<<32 * 512, 256, 0, stream>>>(x, out);  // 1 block per plane
}